// Round 18
// baseline (380.601 us; speedup 1.0000x reference)
//
#include <hip/hip_runtime.h>

#define TPB 256
#define ROWN 8192
#define CAND_MAX 1024
#define HOT_MAX 192
#define EPS_TINY 1.1754943508222875e-38f   // np.finfo(np.float32).tiny

__device__ __forceinline__ unsigned rotl32(unsigned x, int r) {
  return (x << r) | (x >> (32 - r));
}

// threefry2x32, key (0,42), partitionable counters: ctr=(0,idx), bits = x0^x1.
// Verified on-device (r11 decode; r12-r17 absmax 0.0).
__device__ __forceinline__ unsigned tf_pxor(unsigned idx) {
  const unsigned ks0 = 0u, ks1 = 42u, ks2 = 0x1BD11BDAu ^ 0u ^ 42u;
  unsigned x0 = ks0;
  unsigned x1 = idx + ks1;
#define TF4(a,b,cc,d) \
  x0 += x1; x1 = rotl32(x1,(a));  x1 ^= x0; \
  x0 += x1; x1 = rotl32(x1,(b));  x1 ^= x0; \
  x0 += x1; x1 = rotl32(x1,(cc)); x1 ^= x0; \
  x0 += x1; x1 = rotl32(x1,(d));  x1 ^= x0;
  TF4(13,15,26,6)   x0 += ks1; x1 += ks2 + 1u;
  TF4(17,29,16,24)  x0 += ks2; x1 += ks0 + 2u;
  TF4(13,15,26,6)   x0 += ks0; x1 += ks1 + 3u;
  TF4(17,29,16,24)  x0 += ks1; x1 += ks2 + 4u;
  TF4(13,15,26,6)   x0 += ks2; x1 += ks0 + 5u;
#undef TF4
  return x0 ^ x1;
}

// EXACT jax gumbel (precise ocml logf) — wave-dense, candidates only.
__device__ __forceinline__ float gumbel_of(unsigned idx) {
  const unsigned bits = tf_pxor(idx);
  float u = __uint_as_float((bits >> 9) | 0x3f800000u) - 1.0f;
  u = u + EPS_TINY;
  u = fmaxf(EPS_TINY, u);
  return -logf(-logf(u));
}

// APPROX gumbel for the filter pass: |err| <= ~2e-4 (proven r15-r17).
__device__ __forceinline__ float approx_gumbel(unsigned bits) {
  float u = __uint_as_float((bits >> 9) | 0x3f800000u) - 1.0f;
  u = u + EPS_TINY;
  u = fmaxf(EPS_TINY, u);
  float t;
  if (u >= 0.75f) {
    const float v = 1.0f - u;   // exact (Sterbenz)
    t = v * (1.0f + v * (0.5f + v * (0.33333334f + v * (0.25f + v * 0.2f))));
  } else {
    t = -0.69314718f * __log2f(u);
  }
  return -0.69314718f * __log2f(t);
}

// ---------------- fused kernel: one block per row + last-block expansion ----------------
__global__ __launch_bounds__(TPB)
void topk_fused(const void* __restrict__ scores_raw,
                unsigned* __restrict__ ws_cnt,   // [512] group counters (zeroed per launch)
                unsigned* __restrict__ ws_idx,   // [2048][32] selected indices
                float* __restrict__ out,
                int use_ws) {
  const int t    = threadIdx.x;
  const int lane = t & 63;
  const int wave = t >> 6;

  // XCD swizzle (r13-proven): all rows of one b on one XCD -> L2-local exchange
  const int i   = blockIdx.x;           // 0..2047
  const int xcd = i & 7;
  const int k   = i >> 3;
  const int b   = xcd + 8 * (k >> 3);
  const int mem = k & 7;
  const int e   = mem & 3;
  const int rep = mem >> 2;
  const int r   = rep * 1024 + b * 4 + e;
  const int grp = rep * 256 + b;        // output group

  __shared__ float    cf[CAND_MAX];
  __shared__ float    ckh[CAND_MAX];
  __shared__ int      cidx[CAND_MAX];
  __shared__ float    hotK[HOT_MAX];
  __shared__ int      hotI[HOT_MAX];
  __shared__ int      sellist[32];
  __shared__ float    redM[4];
  __shared__ float    redZ[4];
  __shared__ float    redV[4];
  __shared__ int      redI[4];
  __shared__ int      redS[4];
  __shared__ int      wtot[10][4];
  __shared__ int      hotw[4];
  __shared__ int      f32flag;
  __shared__ int      amlast;

  // ---- input dtype autodetect (4 KB prefix; proven r11-r17) ----
  if (t == 0) f32flag = 0;
  __syncthreads();
  {
    const unsigned* w = (const unsigned*)scores_raw;
    bool bad = false;
#pragma unroll
    for (int q = 0; q < 4; ++q) {
      const unsigned x = w[t + 256 * q];
      const float flo = __uint_as_float((x & 0xFFFFu) << 16);
      const float fhi = __uint_as_float(x & 0xFFFF0000u);
      if (!(fabsf(flo) <= 16.0f) || !(fabsf(fhi) <= 16.0f)) bad = true;
    }
    if (bad) f32flag = 1;
  }
  __syncthreads();
  const bool in_f32 = (f32flag != 0);

  // ---- gen (approx filter values, registers) ----
  const unsigned gbase = (unsigned)r * (unsigned)ROWN;
  const size_t ebase0 = ((size_t)b * ROWN + (size_t)t) * 4 + (size_t)e;
  float f[32];
  if (in_f32) {
    const float* sp = (const float*)scores_raw;
#pragma unroll
    for (int j = 0; j < 32; ++j)
      f[j] = sp[ebase0 + (size_t)(256 * j) * 4]
           + approx_gumbel(tf_pxor(gbase + (unsigned)(t + 256 * j)));
  } else {
    const unsigned short* sp = (const unsigned short*)scores_raw;
#pragma unroll
    for (int j = 0; j < 32; ++j)
      f[j] = __uint_as_float(((unsigned)sp[ebase0 + (size_t)(256 * j) * 4]) << 16)
           + approx_gumbel(tf_pxor(gbase + (unsigned)(t + 256 * j)));
  }

  // ---- block max of approx f ----
  float m = f[0];
#pragma unroll
  for (int j = 1; j < 32; ++j) m = fmaxf(m, f[j]);
#pragma unroll
  for (int off = 32; off >= 1; off >>= 1) m = fmaxf(m, __shfl_xor(m, off));
  if (lane == 0) redM[wave] = m;
  __syncthreads();
  m = fmaxf(fmaxf(redM[0], redM[1]), fmaxf(redM[2], redM[3]));

  // ---- bisect theta33 (8 iters; lo < f33 strictly -> margin proof intact) ----
  float lo = m - 25.0f, hi = m;
#pragma unroll 1
  for (int itb = 0; itb < 8; ++itb) {
    const float mid = 0.5f * (lo + hi);
    int c = 0;
#pragma unroll
    for (int j = 0; j < 32; ++j) c += (f[j] > mid) ? 1 : 0;
#pragma unroll
    for (int off = 32; off >= 1; off >>= 1) c += __shfl_xor(c, off);
    if (lane == 0) wtot[itb][wave] = c;
    __syncthreads();
    const int tot = wtot[itb][0] + wtot[itb][1] + wtot[itb][2] + wtot[itb][3];
    if (tot >= 33) lo = mid; else hi = mid;
  }
  const float theta = lo - 2.33f;   // covers all penalizable / top-32 (r12-r17)

  // ---- compact candidate indices ----
  int cj = 0;
#pragma unroll
  for (int j = 0; j < 32; ++j) cj += (f[j] > theta) ? 1 : 0;
  int incv = cj;
#pragma unroll
  for (int off = 1; off < 64; off <<= 1) {
    const int v = __shfl_up(incv, off);
    if (lane >= off) incv += v;
  }
  if (lane == 63) wtot[9][wave] = incv;
  __syncthreads();
  int base = 0;
  for (int w = 0; w < wave; ++w) base += wtot[9][w];
  int cnt = wtot[9][0] + wtot[9][1] + wtot[9][2] + wtot[9][3];
  if (cnt > CAND_MAX) cnt = CAND_MAX;
  int o = base + incv - cj;
#pragma unroll
  for (int j = 0; j < 32; ++j) {
    if (f[j] > theta) {
      if (o < CAND_MAX) cidx[o] = t + 256 * j;
      ++o;
    }
  }
  __syncthreads();

  // ---- dense EXACT recompute (bit-exact cf) ----
#pragma unroll
  for (int kk = 0; kk < 4; ++kk) {
    const int ci = t + 256 * kk;
    if (ci < cnt) {
      const int n = cidx[ci];
      const size_t ei = ((size_t)b * ROWN + (size_t)n) * 4 + (size_t)e;
      float sc;
      if (in_f32) sc = ((const float*)scores_raw)[ei];
      else sc = __uint_as_float(((unsigned)((const unsigned short*)scores_raw)[ei]) << 16);
      cf[ci]  = sc + gumbel_of(gbase + (unsigned)n);
      ckh[ci] = 0.0f;
    }
  }
  __syncthreads();

  // ---- 32 np-faithful dynamics iterations (3 barriers/iter; r16-proven) ----
#pragma unroll 1
  for (int it = 0; it < 32; ++it) {
    float lm = -3.4e38f;
#pragma unroll
    for (int kk = 0; kk < 4; ++kk) {
      const int ci = t + 256 * kk;
      if (ci < cnt) lm = fmaxf(lm, cf[ci]);
    }
#pragma unroll
    for (int off = 32; off >= 1; off >>= 1) lm = fmaxf(lm, __shfl_xor(lm, off));
    if (lane == 0) redM[wave] = lm;
    __syncthreads();                                   // B1
    const float m2 = fmaxf(fmaxf(redM[0], redM[1]), fmaxf(redM[2], redM[3]));
    const float xm = m2 / 0.1f;

    float ek[4];
    float ls = 0.0f;
#pragma unroll
    for (int kk = 0; kk < 4; ++kk) {
      const int ci = t + 256 * kk;
      float ev = 0.0f;
      if (ci < cnt) {
        const float fv = cf[ci];
        if (fv - m2 > -10.398f) { ev = expf(fv / 0.1f - xm); ls += ev; }
      }
      ek[kk] = ev;
    }
#pragma unroll
    for (int off = 32; off >= 1; off >>= 1) ls += __shfl_xor(ls, off);
    if (lane == 0) redZ[wave] = ls;
    __syncthreads();                                   // B2
    const float Z = (redZ[0] + redZ[1]) + (redZ[2] + redZ[3]);

#pragma unroll
    for (int kk = 0; kk < 4; ++kk) {
      const int ci = t + 256 * kk;
      if (ci < cnt && ek[kk] > 0.0f) {
        const float p = ek[kk] / Z;
        ckh[ci] += p;
        const float msk = 1.0f - p;
        if (msk != 1.0f) cf[ci] += logf(fmaxf(msk, EPS_TINY));
      }
    }
    __syncthreads();                                   // B3
  }

  // ---- hot compaction (khot > 0; provably contains the full top-32) ----
  int hk = 0;
#pragma unroll
  for (int kk = 0; kk < 4; ++kk) {
    const int ci = t + 256 * kk;
    hk += (ci < cnt && ckh[ci] > 0.0f) ? 1 : 0;
  }
  int hinc = hk;
#pragma unroll
  for (int off = 1; off < 64; off <<= 1) {
    const int v = __shfl_up(hinc, off);
    if (lane >= off) hinc += v;
  }
  if (lane == 63) hotw[wave] = hinc;
  __syncthreads();
  int hbase = 0;
  for (int w = 0; w < wave; ++w) hbase += hotw[w];
  const int hotcnt = hotw[0] + hotw[1] + hotw[2] + hotw[3];
  int ho = hbase + hinc - hk;
  if (hotcnt <= HOT_MAX) {
#pragma unroll
    for (int kk = 0; kk < 4; ++kk) {
      const int ci = t + 256 * kk;
      if (ci < cnt && ckh[ci] > 0.0f) { hotK[ho] = ckh[ci]; hotI[ho] = cidx[ci]; ++ho; }
    }
  }
  __syncthreads();

  if (hotcnt >= 32 && hotcnt <= HOT_MAX) {
    // ---- wave-0 register top-32 (3 slots/lane, no barriers in loop) ----
    if (wave == 0) {
      float kv[3]; int ki[3];
#pragma unroll
      for (int s = 0; s < 3; ++s) {
        const int h = lane + 64 * s;
        if (h < hotcnt) { kv[s] = hotK[h]; ki[s] = hotI[h]; }
        else            { kv[s] = -3.4e38f; ki[s] = 0x7FFFFFFF; }
      }
#pragma unroll 1
      for (int pass = 0; pass < 32; ++pass) {
        float bv = kv[0]; int bi = ki[0];
#pragma unroll
        for (int s = 1; s < 3; ++s)
          if (kv[s] > bv || (kv[s] == bv && ki[s] < bi)) { bv = kv[s]; bi = ki[s]; }
#pragma unroll
        for (int off = 32; off >= 1; off >>= 1) {
          const float ov = __shfl_xor(bv, off);
          const int   oi = __shfl_xor(bi, off);
          if (ov > bv || (ov == bv && oi < bi)) { bv = ov; bi = oi; }
        }
        if (lane == 0) sellist[pass] = bi;
#pragma unroll
        for (int s = 0; s < 3; ++s)
          if (ki[s] == bi) kv[s] = -3.4e38f;
      }
    }
    __syncthreads();
  } else {
    // ---- fallback: LDS top-k over all candidates (r16-proven) ----
#pragma unroll 1
    for (int pass = 0; pass < 32; ++pass) {
      float bv = -3.4e38f; int bi = 0x7FFFFFFF, bs = 0;
#pragma unroll
      for (int kk = 0; kk < 4; ++kk) {
        const int ci = t + 256 * kk;
        if (ci < cnt) {
          const float v = ckh[ci];
          const int ix = cidx[ci];
          if (v > bv || (v == bv && ix < bi)) { bv = v; bi = ix; bs = ci; }
        }
      }
#pragma unroll
      for (int off = 32; off >= 1; off >>= 1) {
        const float ov = __shfl_xor(bv, off);
        const int   oi = __shfl_xor(bi, off);
        const int   os = __shfl_xor(bs, off);
        if (ov > bv || (ov == bv && oi < bi)) { bv = ov; bi = oi; bs = os; }
      }
      if (lane == 0) { redV[wave] = bv; redI[wave] = bi; redS[wave] = bs; }
      __syncthreads();
      if (t == 0) {
        float wv = redV[0]; int wi = redI[0], ws2 = redS[0];
#pragma unroll
        for (int w = 1; w < 4; ++w) {
          const float ov = redV[w]; const int oi = redI[w], os = redS[w];
          if (ov > wv || (ov == wv && oi < wi)) { wv = ov; wi = oi; ws2 = os; }
        }
        sellist[pass] = wi;
        ckh[ws2] = -3.4e38f;
      }
      __syncthreads();
    }
  }

  if (use_ws) {
    // publish this row's selection, then last block of the group expands
    if (t < 32) ws_idx[r * 32 + t] = (unsigned)sellist[t];
    __threadfence();
    if (t == 0) amlast = (atomicAdd(&ws_cnt[grp], 1u) == 3u) ? 1 : 0;
    __syncthreads();
    if (amlast) {
      // expander: bitmap in LDS (alias dead cf) -> coalesced float4 slab
      unsigned* ebm = (unsigned*)cf;           // 4 x 256 words
#pragma unroll
      for (int q = 0; q < 4; ++q) ebm[t + 256 * q] = 0u;
      __syncthreads();
      if (t < 4) {
        const volatile unsigned* vws = ws_idx + (size_t)(rep * 1024 + b * 4 + t) * 32;
#pragma unroll 1
        for (int p = 0; p < 32; ++p) {
          const unsigned ix = vws[p];
          ebm[t * 256 + (ix >> 5)] |= (1u << (ix & 31));
        }
      }
      __syncthreads();
      float4* out4 = (float4*)out;
      const size_t obase = (size_t)grp * ROWN;
#pragma unroll 1
      for (int j = 0; j < 32; ++j) {
        const int n = t + 256 * j;
        float4 v;
        v.x = ((ebm[0 * 256 + (n >> 5)] >> (n & 31)) & 1u) ? 1.0f : 0.0f;
        v.y = ((ebm[1 * 256 + (n >> 5)] >> (n & 31)) & 1u) ? 1.0f : 0.0f;
        v.z = ((ebm[2 * 256 + (n >> 5)] >> (n & 31)) & 1u) ? 1.0f : 0.0f;
        v.w = ((ebm[3 * 256 + (n >> 5)] >> (n & 31)) & 1u) ? 1.0f : 0.0f;
        out4[obase + (size_t)n] = v;
      }
    }
  } else {
    // fallback: direct strided write of this row
    unsigned* bm = (unsigned*)ckh;   // 256 words, dead after top-k
    if (t < ROWN / 32) bm[t] = 0u;
    __syncthreads();
    if (t == 0) {
#pragma unroll 1
      for (int p = 0; p < 32; ++p) {
        const int ix = sellist[p];
        bm[ix >> 5] |= (1u << (ix & 31));
      }
    }
    __syncthreads();
    float* op = out + ((size_t)grp * ROWN) * 4 + (size_t)e;
#pragma unroll 1
    for (int j = 0; j < 32; ++j) {
      const int n = t + 256 * j;
      op[(size_t)n * 4] = ((bm[n >> 5] >> (n & 31)) & 1u) ? 1.0f : 0.0f;
    }
  }
}

extern "C" void kernel_launch(void* const* d_in, const int* in_sizes, int n_in,
                              void* d_out, int out_size, void* d_ws, size_t ws_size,
                              hipStream_t stream) {
  const void* scores = d_in[0];    // dtype autodetected in-kernel
  float* out = (float*)d_out;      // f32 output (established r11)
  const size_t need = 512u * 4u + 2048u * 32u * 4u;   // counters + index lists
  const int use_ws = (ws_size >= need) ? 1 : 0;
  unsigned* cnt = (unsigned*)d_ws;
  unsigned* idx = cnt + 512;
  if (use_ws) hipMemsetAsync(d_ws, 0, 512 * sizeof(unsigned), stream);
  topk_fused<<<dim3(2048), dim3(TPB), 0, stream>>>(scores, cnt, idx, out, use_ws);
}

// Round 19
// 278.669 us; speedup vs baseline: 1.3658x; 1.3658x over previous
//
#include <hip/hip_runtime.h>

#define TPB 256
#define ROWN 8192
#define CMAX 1024   // per-row candidate cap (r12-r18 proven never hit)
#define EPS_TINY 1.1754943508222875e-38f   // np.finfo(np.float32).tiny

__device__ __forceinline__ unsigned rotl32(unsigned x, int r) {
  return (x << r) | (x >> (32 - r));
}

// threefry2x32, key (0,42), partitionable counters: ctr=(0,idx), bits = x0^x1.
// Verified on-device (r11 decode; r12-r18 absmax 0.0).
__device__ __forceinline__ unsigned tf_pxor(unsigned idx) {
  const unsigned ks0 = 0u, ks1 = 42u, ks2 = 0x1BD11BDAu ^ 0u ^ 42u;
  unsigned x0 = ks0;
  unsigned x1 = idx + ks1;
#define TF4(a,b,cc,d) \
  x0 += x1; x1 = rotl32(x1,(a));  x1 ^= x0; \
  x0 += x1; x1 = rotl32(x1,(b));  x1 ^= x0; \
  x0 += x1; x1 = rotl32(x1,(cc)); x1 ^= x0; \
  x0 += x1; x1 = rotl32(x1,(d));  x1 ^= x0;
  TF4(13,15,26,6)   x0 += ks1; x1 += ks2 + 1u;
  TF4(17,29,16,24)  x0 += ks2; x1 += ks0 + 2u;
  TF4(13,15,26,6)   x0 += ks0; x1 += ks1 + 3u;
  TF4(17,29,16,24)  x0 += ks1; x1 += ks2 + 4u;
  TF4(13,15,26,6)   x0 += ks2; x1 += ks0 + 5u;
#undef TF4
  return x0 ^ x1;
}

// EXACT jax gumbel (precise ocml logf) — candidates only, bit-exact.
__device__ __forceinline__ float gumbel_of(unsigned idx) {
  const unsigned bits = tf_pxor(idx);
  float u = __uint_as_float((bits >> 9) | 0x3f800000u) - 1.0f;
  u = u + EPS_TINY;
  u = fmaxf(EPS_TINY, u);
  return -logf(-logf(u));
}

// APPROX gumbel for the filter pass: |err| <= ~2e-4 (proven r15-r18).
__device__ __forceinline__ float approx_gumbel(unsigned bits) {
  float u = __uint_as_float((bits >> 9) | 0x3f800000u) - 1.0f;
  u = u + EPS_TINY;
  u = fmaxf(EPS_TINY, u);
  float t;
  if (u >= 0.75f) {
    const float v = 1.0f - u;   // exact (Sterbenz)
    t = v * (1.0f + v * (0.5f + v * (0.33333334f + v * (0.25f + v * 0.2f))));
  } else {
    t = -0.69314718f * __log2f(u);
  }
  return -0.69314718f * __log2f(t);
}

// ---------------- fused: one block per (rep,b) group; wave-per-row dynamics ----------------
__global__ __launch_bounds__(TPB)
void topk_group(const void* __restrict__ scores_raw, float4* __restrict__ out4) {
  const int t    = threadIdx.x;
  const int lane = t & 63;
  const int wave = t >> 6;

  // XCD swizzle: rep0/rep1 blocks of the same b share an XCD (input L2 reuse).
  const int g   = blockIdx.x;          // 0..511
  const int xcd = g & 7;
  const int qq  = g >> 3;              // 0..63
  const int b   = xcd + 8 * (qq & 31);
  const int rep = qq >> 5;
  const int grp = rep * 256 + b;

  __shared__ int   candIdx[4][CMAX];   // 16 KB; aliased as bitmap in phase 3
  __shared__ int   cnts[4];
  __shared__ int   sel[4][32];
  __shared__ float redM[4];
  __shared__ int   wtot[13][4];
  __shared__ int   f32flag;

  // ---- input dtype autodetect (4 KB prefix; proven r11-r18) ----
  if (t == 0) f32flag = 0;
  __syncthreads();
  {
    const unsigned* w = (const unsigned*)scores_raw;
    bool bad = false;
#pragma unroll
    for (int q = 0; q < 4; ++q) {
      const unsigned x = w[t + 256 * q];
      const float flo = __uint_as_float((x & 0xFFFFu) << 16);
      const float fhi = __uint_as_float(x & 0xFFFF0000u);
      if (!(fabsf(flo) <= 16.0f) || !(fabsf(fhi) <= 16.0f)) bad = true;
    }
    if (bad) f32flag = 1;
  }
  __syncthreads();
  const bool in_f32 = (f32flag != 0);

  // ================= phase 1: per e-row gen -> theta -> compact =================
#pragma unroll 1
  for (int e = 0; e < 4; ++e) {
    const int r = rep * 1024 + b * 4 + e;
    const unsigned gbase = (unsigned)r * (unsigned)ROWN;
    const size_t ebase0 = ((size_t)b * ROWN + (size_t)t) * 4 + (size_t)e;

    float f[32];
    if (in_f32) {
      const float* sp = (const float*)scores_raw;
#pragma unroll
      for (int j = 0; j < 32; ++j)
        f[j] = sp[ebase0 + (size_t)(256 * j) * 4]
             + approx_gumbel(tf_pxor(gbase + (unsigned)(t + 256 * j)));
    } else {
      const unsigned short* sp = (const unsigned short*)scores_raw;
#pragma unroll
      for (int j = 0; j < 32; ++j)
        f[j] = __uint_as_float(((unsigned)sp[ebase0 + (size_t)(256 * j) * 4]) << 16)
             + approx_gumbel(tf_pxor(gbase + (unsigned)(t + 256 * j)));
    }

    // block max
    float m = f[0];
#pragma unroll
    for (int j = 1; j < 32; ++j) m = fmaxf(m, f[j]);
#pragma unroll
    for (int off = 32; off >= 1; off >>= 1) m = fmaxf(m, __shfl_xor(m, off));
    if (lane == 0) redM[wave] = m;
    __syncthreads();
    m = fmaxf(fmaxf(redM[0], redM[1]), fmaxf(redM[2], redM[3]));

    // bisect theta33 (12 iters, resolution 25/4096 ~ 6e-3)
    float lo = m - 25.0f, hi = m;
#pragma unroll 1
    for (int itb = 0; itb < 12; ++itb) {
      const float mid = 0.5f * (lo + hi);
      int c = 0;
#pragma unroll
      for (int j = 0; j < 32; ++j) c += (f[j] > mid) ? 1 : 0;
#pragma unroll
      for (int off = 32; off >= 1; off >>= 1) c += __shfl_xor(c, off);
      if (lane == 0) wtot[itb][wave] = c;
      __syncthreads();
      const int tot = wtot[itb][0] + wtot[itb][1] + wtot[itb][2] + wtot[itb][3];
      if (tot >= 33) lo = mid; else hi = mid;
    }
    const float theta = lo - 2.34f;   // superset proof margin (r12-r18)

    // compact candidate indices (deterministic prefix order)
    int cj = 0;
#pragma unroll
    for (int j = 0; j < 32; ++j) cj += (f[j] > theta) ? 1 : 0;
    int incv = cj;
#pragma unroll
    for (int off = 1; off < 64; off <<= 1) {
      const int v = __shfl_up(incv, off);
      if (lane >= off) incv += v;
    }
    if (lane == 63) wtot[12][wave] = incv;
    __syncthreads();
    int base = 0;
    for (int w = 0; w < wave; ++w) base += wtot[12][w];
    int cnt = wtot[12][0] + wtot[12][1] + wtot[12][2] + wtot[12][3];
    if (cnt > CMAX) cnt = CMAX;
    if (t == 0) cnts[e] = cnt;
    int o = base + incv - cj;
#pragma unroll
    for (int j = 0; j < 32; ++j) {
      if (f[j] > theta) {
        if (o < CMAX) candIdx[e][o] = t + 256 * j;
        ++o;
      }
    }
    __syncthreads();
  }

  // ================= phase 2: wave e runs row e — NO barriers =================
  {
    const int e = wave;
    const int cnt = cnts[e];
    const unsigned gbase = (unsigned)(rep * 1024 + b * 4 + e) * (unsigned)ROWN;

    float cfr[16], khr[16];
    int   idxr[16];
#pragma unroll
    for (int q = 0; q < 16; ++q) {
      cfr[q] = -3.0e38f; khr[q] = -3.0e38f; idxr[q] = 0x7FFFFFFF;
      if (64 * q < cnt) {              // wave-uniform chunk skip
        const int ci = lane + 64 * q;
        if (ci < cnt) {
          const int n = candIdx[e][ci];
          const size_t ei = ((size_t)b * ROWN + (size_t)n) * 4 + (size_t)e;
          float sc;
          if (in_f32) sc = ((const float*)scores_raw)[ei];
          else sc = __uint_as_float(((unsigned)((const unsigned short*)scores_raw)[ei]) << 16);
          cfr[q] = sc + gumbel_of(gbase + (unsigned)n);   // bit-exact
          khr[q] = 0.0f;
          idxr[q] = n;
        }
      }
    }

    // 32 np-faithful dynamics iterations, wave-local (12 shfl DS per iter)
#pragma unroll 1
    for (int it = 0; it < 32; ++it) {
      float m2 = -3.4e38f;
#pragma unroll
      for (int q = 0; q < 16; ++q)
        if (64 * q < cnt) m2 = fmaxf(m2, cfr[q]);
#pragma unroll
      for (int off = 32; off >= 1; off >>= 1) m2 = fmaxf(m2, __shfl_xor(m2, off));
      const float xm = m2 / 0.1f;

      float ek[16];
      float Z = 0.0f;
#pragma unroll
      for (int q = 0; q < 16; ++q) {
        float ev = 0.0f;
        if (64 * q < cnt) {
          if (cfr[q] - m2 > -10.398f) { ev = expf(cfr[q] / 0.1f - xm); Z += ev; }
        }
        ek[q] = ev;
      }
#pragma unroll
      for (int off = 32; off >= 1; off >>= 1) Z += __shfl_xor(Z, off);

#pragma unroll
      for (int q = 0; q < 16; ++q) {
        if (64 * q < cnt && ek[q] > 0.0f) {
          const float p = ek[q] / Z;
          khr[q] += p;
          const float msk = 1.0f - p;
          if (msk != 1.0f) cfr[q] += logf(fmaxf(msk, EPS_TINY));
        }
      }
    }

    // top-32 of khot, lowest-n tie-break, wave-local
#pragma unroll 1
    for (int pass = 0; pass < 32; ++pass) {
      float bv = -3.4e38f; int bi = 0x7FFFFFFF;
#pragma unroll
      for (int q = 0; q < 16; ++q) {
        if (64 * q < cnt) {
          const float v = khr[q]; const int ix = idxr[q];
          if (v > bv || (v == bv && ix < bi)) { bv = v; bi = ix; }
        }
      }
#pragma unroll
      for (int off = 32; off >= 1; off >>= 1) {
        const float ov = __shfl_xor(bv, off);
        const int   oi = __shfl_xor(bi, off);
        if (ov > bv || (ov == bv && oi < bi)) { bv = ov; bi = oi; }
      }
      if (lane == 0) sel[e][pass] = bi;
#pragma unroll
      for (int q = 0; q < 16; ++q)
        if (64 * q < cnt && idxr[q] == bi) khr[q] = -3.0e38f;
    }
  }
  __syncthreads();

  // ================= phase 3: bitmap expand -> coalesced float4 slab =================
  unsigned* ebm = (unsigned*)&candIdx[0][0];   // 4 x 256 words (candIdx dead)
#pragma unroll
  for (int q = 0; q < 4; ++q) ebm[t + 256 * q] = 0u;
  __syncthreads();
  if (t < 4) {
#pragma unroll 1
    for (int p = 0; p < 32; ++p) {
      const int ix = sel[t][p];
      ebm[t * 256 + (ix >> 5)] |= (1u << (ix & 31));
    }
  }
  __syncthreads();

  const size_t obase = (size_t)grp * ROWN;
#pragma unroll 1
  for (int j = 0; j < 32; ++j) {
    const int n = t + 256 * j;
    float4 v;
    v.x = ((ebm[0 * 256 + (n >> 5)] >> (n & 31)) & 1u) ? 1.0f : 0.0f;
    v.y = ((ebm[1 * 256 + (n >> 5)] >> (n & 31)) & 1u) ? 1.0f : 0.0f;
    v.z = ((ebm[2 * 256 + (n >> 5)] >> (n & 31)) & 1u) ? 1.0f : 0.0f;
    v.w = ((ebm[3 * 256 + (n >> 5)] >> (n & 31)) & 1u) ? 1.0f : 0.0f;
    out4[obase + (size_t)n] = v;
  }
}

extern "C" void kernel_launch(void* const* d_in, const int* in_sizes, int n_in,
                              void* d_out, int out_size, void* d_ws, size_t ws_size,
                              hipStream_t stream) {
  const void* scores = d_in[0];    // dtype autodetected in-kernel
  float4* out = (float4*)d_out;    // f32 output (established r11)
  topk_group<<<dim3(512), dim3(TPB), 0, stream>>>(scores, out);
}